// Round 1
// baseline (210.145 us; speedup 1.0000x reference)
//
#include <hip/hip_runtime.h>

#define TIMESTEPS 1000
#define BATCH 64
#define HH 256
#define WW 256

// One block per (b, x) row. 256 threads = one per w (the "y" scatter value).
// Build per-row scatter-max histograms for both images in LDS, then sum
// squared bin differences exactly in integers.
__global__ __launch_bounds__(256) void holo_mse_kernel(
    const float* __restrict__ rec, const float* __restrict__ tgt,
    unsigned long long* __restrict__ acc)
{
    __shared__ int h_rec[TIMESTEPS];
    __shared__ int h_tgt[TIMESTEPS];

    const int row = blockIdx.x;          // row = b*HH + x
    const int tid = threadIdx.x;         // w index (the scattered value)

    for (int t = tid; t < TIMESTEPS; t += 256) { h_rec[t] = 0; h_tgt[t] = 0; }
    __syncthreads();

    const float vr = rec[(size_t)row * WW + tid];
    const float vt = tgt[(size_t)row * WW + tid];

    if (vr != 0.0f) {
        int t = (int)(vr * 1000.0f) - 1;   // trunc toward zero, matches astype(int32)
        if (t < 0) t += TIMESTEPS;         // python negative-index wrap (-1 -> 999)
        if (t >= 0 && t < TIMESTEPS) atomicMax(&h_rec[t], tid);  // OOB -> drop
    }
    if (vt != 0.0f) {
        int t = (int)(vt * 1000.0f) - 1;
        if (t < 0) t += TIMESTEPS;
        if (t >= 0 && t < TIMESTEPS) atomicMax(&h_tgt[t], tid);
    }
    __syncthreads();

    // Per-row sum of squared diffs: <= 1000 * 255^2 < 2^31, exact in int32.
    int part = 0;
    for (int t = tid; t < TIMESTEPS; t += 256) {
        int d = h_rec[t] - h_tgt[t];
        part += d * d;
    }

    // wave-64 shuffle reduce, then cross-wave via LDS
    #pragma unroll
    for (int off = 32; off > 0; off >>= 1) part += __shfl_down(part, off, 64);

    __shared__ int wsum[4];
    const int wave = tid >> 6;
    if ((tid & 63) == 0) wsum[wave] = part;
    __syncthreads();

    if (tid == 0) {
        long long tot = (long long)wsum[0] + (long long)wsum[1]
                      + (long long)wsum[2] + (long long)wsum[3];
        atomicAdd(acc, (unsigned long long)tot);   // integer: deterministic + exact
    }
}

__global__ void finalize_kernel(const unsigned long long* __restrict__ acc,
                                float* __restrict__ out)
{
    const double denom = (double)BATCH * (double)HH * (double)TIMESTEPS; // 16,384,000
    out[0] = (float)((double)(*acc) / denom);
}

extern "C" void kernel_launch(void* const* d_in, const int* in_sizes, int n_in,
                              void* d_out, int out_size, void* d_ws, size_t ws_size,
                              hipStream_t stream) {
    const float* rec = (const float*)d_in[0];
    const float* tgt = (const float*)d_in[1];
    float* out = (float*)d_out;
    unsigned long long* acc = (unsigned long long*)d_ws;

    // d_ws is poisoned (0xAA) before timing and NOT re-poisoned between
    // replays — zero the accumulator ourselves every call.
    hipMemsetAsync(acc, 0, sizeof(unsigned long long), stream);

    holo_mse_kernel<<<BATCH * HH, 256, 0, stream>>>(rec, tgt, acc);
    finalize_kernel<<<1, 1, 0, stream>>>(acc, out);
}

// Round 2
// 20.311 us; speedup vs baseline: 10.3462x; 10.3462x over previous
//
#include <hip/hip_runtime.h>

#define TIMESTEPS 1000
#define BATCH 64
#define HH 256
#define WW 256
#define ROWS_PER_BLOCK 8
#define NBLOCKS ((BATCH * HH) / ROWS_PER_BLOCK)   // 2048

// Each block handles 8 (b,x) rows. Per row: build scatter-max histograms for
// both images in LDS (atomicMax; last-write-wins == max-y), accumulate exact
// integer sum of squared bin diffs in registers. One partial per block goes
// to its own d_ws slot -> no contended atomics anywhere.
__global__ __launch_bounds__(256) void holo_mse_kernel(
    const float* __restrict__ rec, const float* __restrict__ tgt,
    unsigned int* __restrict__ partials)
{
    __shared__ int h_rec[TIMESTEPS];
    __shared__ int h_tgt[TIMESTEPS];

    const int tid = threadIdx.x;                  // w index (scattered value)
    const int row0 = blockIdx.x * ROWS_PER_BLOCK;

    // per-thread exact integer accumulator:
    // max per row = 1000 * 255^2 ~= 65M; 8 rows spread over 256 threads -> ~2M. Safe.
    unsigned int total = 0;

    for (int r = 0; r < ROWS_PER_BLOCK; ++r) {
        const int row = row0 + r;

        for (int t = tid; t < TIMESTEPS; t += 256) { h_rec[t] = 0; h_tgt[t] = 0; }
        __syncthreads();

        const float vr = rec[(size_t)row * WW + tid];
        const float vt = tgt[(size_t)row * WW + tid];

        if (vr != 0.0f) {
            int t = (int)(vr * 1000.0f) - 1;   // trunc toward zero == astype(int32)
            if (t < 0) t += TIMESTEPS;         // python wrap: -1 -> 999
            if (t >= 0 && t < TIMESTEPS) atomicMax(&h_rec[t], tid);  // OOB drop
        }
        if (vt != 0.0f) {
            int t = (int)(vt * 1000.0f) - 1;
            if (t < 0) t += TIMESTEPS;
            if (t >= 0 && t < TIMESTEPS) atomicMax(&h_tgt[t], tid);
        }
        __syncthreads();

        for (int t = tid; t < TIMESTEPS; t += 256) {
            int d = h_rec[t] - h_tgt[t];
            total += (unsigned int)(d * d);
        }
        __syncthreads();   // before re-zeroing in next row iteration
    }

    // block reduce: wave-64 shuffle, then cross-wave via LDS
    #pragma unroll
    for (int off = 32; off > 0; off >>= 1) total += __shfl_down(total, off, 64);

    __shared__ unsigned int wsum[4];
    const int wave = tid >> 6;
    if ((tid & 63) == 0) wsum[wave] = total;
    __syncthreads();

    if (tid == 0)
        partials[blockIdx.x] = wsum[0] + wsum[1] + wsum[2] + wsum[3];  // <= 8*65M < 2^32
}

// Single block sums the 2048 partials exactly in u64, divides once.
__global__ __launch_bounds__(256) void reduce_kernel(
    const unsigned int* __restrict__ partials, float* __restrict__ out)
{
    const int tid = threadIdx.x;
    unsigned long long s = 0;
    for (int i = tid; i < NBLOCKS; i += 256) s += (unsigned long long)partials[i];

    #pragma unroll
    for (int off = 32; off > 0; off >>= 1) s += __shfl_down(s, off, 64);

    __shared__ unsigned long long wsum[4];
    const int wave = tid >> 6;
    if ((tid & 63) == 0) wsum[wave] = s;
    __syncthreads();

    if (tid == 0) {
        unsigned long long tot = wsum[0] + wsum[1] + wsum[2] + wsum[3];
        const double denom = (double)BATCH * (double)HH * (double)TIMESTEPS; // 16,384,000
        out[0] = (float)((double)tot / denom);
    }
}

extern "C" void kernel_launch(void* const* d_in, const int* in_sizes, int n_in,
                              void* d_out, int out_size, void* d_ws, size_t ws_size,
                              hipStream_t stream) {
    const float* rec = (const float*)d_in[0];
    const float* tgt = (const float*)d_in[1];
    float* out = (float*)d_out;
    unsigned int* partials = (unsigned int*)d_ws;   // 2048 * 4 B = 8 KB scratch

    holo_mse_kernel<<<NBLOCKS, 256, 0, stream>>>(rec, tgt, partials);
    reduce_kernel<<<1, 256, 0, stream>>>(partials, out);
}

// Round 3
// 14.787 us; speedup vs baseline: 14.2112x; 1.3736x over previous
//
#include <hip/hip_runtime.h>

#define TIMESTEPS 1000
#define BATCH 64
#define HH 256
#define WW 256
#define ROWS_PER_WAVE 4
#define WAVES_PER_BLOCK 4
#define NROWS (BATCH * HH)                                   // 16384
#define NBLOCKS (NROWS / (ROWS_PER_WAVE * WAVES_PER_BLOCK))  // 1024
#define HBINS 1024                                           // bins padded 1000 -> 1024
#define NPART (NBLOCKS * WAVES_PER_BLOCK)                    // 4096

// Wave-private histograms + generation tags: no __syncthreads anywhere,
// no per-row zero-init. Entry = (gen<<8) | y ; gen increases per row, so
// atomicMax over same-gen entries is max-y and stale rows always lose.
// Decode: (p - gen<<8) < 256 ? (p - gen<<8) : 0.
__global__ __launch_bounds__(256) void holo_mse_kernel(
    const float* __restrict__ rec, const float* __restrict__ tgt,
    unsigned int* __restrict__ partials)
{
    __shared__ unsigned int hist[WAVES_PER_BLOCK][2][HBINS];  // 32 KB/block

    const int tid  = threadIdx.x;
    const int wave = tid >> 6;
    const int lane = tid & 63;

    unsigned int* hr = &hist[wave][0][0];
    unsigned int* ht = &hist[wave][1][0];

    // one-time init (gen 0 == invalid), contiguous b128 writes: uniform banks
    const uint4 z4 = make_uint4(0u, 0u, 0u, 0u);
    #pragma unroll
    for (int k = 0; k < 4; ++k) {
        *(uint4*)&hr[k * 256 + lane * 4] = z4;
        *(uint4*)&ht[k * 256 + lane * 4] = z4;
    }
    __builtin_amdgcn_wave_barrier();

    unsigned int acc = 0;

    const int row0 = blockIdx.x * (ROWS_PER_WAVE * WAVES_PER_BLOCK) + wave * ROWS_PER_WAVE;

    for (int r = 0; r < ROWS_PER_WAVE; ++r) {
        const int row = row0 + r;
        const unsigned int genHi = (unsigned int)(r + 1) << 8;

        // coalesced 16B/lane loads
        const float4 vr4 = *(const float4*)&rec[(size_t)row * WW + lane * 4];
        const float4 vt4 = *(const float4*)&tgt[(size_t)row * WW + lane * 4];
        const float vr[4] = {vr4.x, vr4.y, vr4.z, vr4.w};
        const float vt[4] = {vt4.x, vt4.y, vt4.z, vt4.w};

        #pragma unroll
        for (int j = 0; j < 4; ++j) {
            const unsigned int y = (unsigned int)(lane * 4 + j);
            if (vr[j] != 0.0f) {
                int t = (int)(vr[j] * 1000.0f) - 1;   // trunc == astype(int32)
                if (t < 0) t += TIMESTEPS;            // python wrap: -1 -> 999
                if ((unsigned)t < TIMESTEPS) atomicMax(&hr[t], genHi | y);
            }
            if (vt[j] != 0.0f) {
                int t = (int)(vt[j] * 1000.0f) - 1;
                if (t < 0) t += TIMESTEPS;
                if ((unsigned)t < TIMESTEPS) atomicMax(&ht[t], genHi | y);
            }
        }
        __builtin_amdgcn_wave_barrier();   // keep reads after atomics

        // accumulate: contiguous b128 reads (k*256 + lane*4 -> all 32 banks)
        #pragma unroll
        for (int k = 0; k < 4; ++k) {
            const uint4 a = *(const uint4*)&hr[k * 256 + lane * 4];
            const uint4 b = *(const uint4*)&ht[k * 256 + lane * 4];
            const unsigned int ar[4] = {a.x, a.y, a.z, a.w};
            const unsigned int br[4] = {b.x, b.y, b.z, b.w};
            #pragma unroll
            for (int j = 0; j < 4; ++j) {
                unsigned int ur = ar[j] - genHi;
                unsigned int yr = (ur < 256u) ? ur : 0u;
                unsigned int ut = br[j] - genHi;
                unsigned int yt = (ut < 256u) ? ut : 0u;
                int d = (int)yr - (int)yt;
                acc += (unsigned int)(d * d);
            }
        }
        __builtin_amdgcn_wave_barrier();   // next row's atomics stay below reads
    }

    // wave-64 shuffle reduce; one partial per wave, zero contention
    #pragma unroll
    for (int off = 32; off > 0; off >>= 1) acc += __shfl_down(acc, off, 64);
    if (lane == 0) partials[blockIdx.x * WAVES_PER_BLOCK + wave] = acc;
}

// Single block sums 4096 u32 partials exactly in u64.
__global__ __launch_bounds__(256) void reduce_kernel(
    const unsigned int* __restrict__ partials, float* __restrict__ out)
{
    const int tid = threadIdx.x;
    unsigned long long s = 0;
    #pragma unroll
    for (int k = 0; k < 4; ++k) {
        const uint4 p = *(const uint4*)&partials[(k * 256 + tid) * 4];
        s += (unsigned long long)p.x + p.y + p.z + p.w;
    }

    #pragma unroll
    for (int off = 32; off > 0; off >>= 1) s += __shfl_down(s, off, 64);

    __shared__ unsigned long long wsum[4];
    const int wave = tid >> 6;
    if ((tid & 63) == 0) wsum[wave] = s;
    __syncthreads();

    if (tid == 0) {
        unsigned long long tot = wsum[0] + wsum[1] + wsum[2] + wsum[3];
        const double denom = (double)BATCH * (double)HH * (double)TIMESTEPS; // 16,384,000
        out[0] = (float)((double)tot / denom);
    }
}

extern "C" void kernel_launch(void* const* d_in, const int* in_sizes, int n_in,
                              void* d_out, int out_size, void* d_ws, size_t ws_size,
                              hipStream_t stream) {
    const float* rec = (const float*)d_in[0];
    const float* tgt = (const float*)d_in[1];
    float* out = (float*)d_out;
    unsigned int* partials = (unsigned int*)d_ws;   // 4096 * 4 B = 16 KB scratch

    holo_mse_kernel<<<NBLOCKS, 256, 0, stream>>>(rec, tgt, partials);
    reduce_kernel<<<1, 256, 0, stream>>>(partials, out);
}

// Round 4
// 14.650 us; speedup vs baseline: 14.3448x; 1.0094x over previous
//
#include <hip/hip_runtime.h>

#define TIMESTEPS 1000
#define BATCH 64
#define HH 256
#define WW 256
#define ROWS_PER_WAVE 4
#define WAVES_PER_BLOCK 4
#define NROWS (BATCH * HH)                                   // 16384
#define NBLOCKS (NROWS / (ROWS_PER_WAVE * WAVES_PER_BLOCK))  // 1024
#define HBINS 1024                                           // bins padded 1000 -> 1024
#define NPART (NBLOCKS * WAVES_PER_BLOCK)                    // 4096

// Wave-private histograms + generation tags: no __syncthreads anywhere, no
// per-row zero-init. Entry = (gen<<8) | y ; gen increases per row, so
// atomicMax over same-gen entries is max-y and stale rows always lose.
// All 8 global float4 loads are issued BEFORE any LDS work so the HBM/L3
// stream overlaps init + scatter instead of serializing per row behind
// wave_barriers.
__global__ __launch_bounds__(256) void holo_mse_kernel(
    const float* __restrict__ rec, const float* __restrict__ tgt,
    unsigned int* __restrict__ partials)
{
    __shared__ unsigned int hist[WAVES_PER_BLOCK][2][HBINS];  // 32 KB/block

    const int tid  = threadIdx.x;
    const int wave = tid >> 6;
    const int lane = tid & 63;

    unsigned int* hr = &hist[wave][0][0];
    unsigned int* ht = &hist[wave][1][0];

    const int row0 = blockIdx.x * (ROWS_PER_WAVE * WAVES_PER_BLOCK) + wave * ROWS_PER_WAVE;

    // ---- issue ALL global loads up front (32 VGPRs of data in flight) ----
    float4 vr4[ROWS_PER_WAVE], vt4[ROWS_PER_WAVE];
    #pragma unroll
    for (int r = 0; r < ROWS_PER_WAVE; ++r) {
        vr4[r] = *(const float4*)&rec[(size_t)(row0 + r) * WW + lane * 4];
        vt4[r] = *(const float4*)&tgt[(size_t)(row0 + r) * WW + lane * 4];
    }

    // one-time init (gen 0 == invalid) overlaps the loads; contiguous b128
    // writes (k*256 + lane*4) hit all 32 banks uniformly.
    const uint4 z4 = make_uint4(0u, 0u, 0u, 0u);
    #pragma unroll
    for (int k = 0; k < 4; ++k) {
        *(uint4*)&hr[k * 256 + lane * 4] = z4;
        *(uint4*)&ht[k * 256 + lane * 4] = z4;
    }
    __builtin_amdgcn_wave_barrier();

    unsigned int acc = 0;

    #pragma unroll
    for (int r = 0; r < ROWS_PER_WAVE; ++r) {
        const unsigned int genHi = (unsigned int)(r + 1) << 8;
        const float vr[4] = {vr4[r].x, vr4[r].y, vr4[r].z, vr4[r].w};
        const float vt[4] = {vt4[r].x, vt4[r].y, vt4[r].z, vt4[r].w};

        #pragma unroll
        for (int j = 0; j < 4; ++j) {
            const unsigned int y = (unsigned int)(lane * 4 + j);
            if (vr[j] != 0.0f) {
                int t = (int)(vr[j] * 1000.0f) - 1;   // trunc == astype(int32)
                if (t < 0) t += TIMESTEPS;            // python wrap: -1 -> 999
                if ((unsigned)t < TIMESTEPS) atomicMax(&hr[t], genHi | y);
            }
            if (vt[j] != 0.0f) {
                int t = (int)(vt[j] * 1000.0f) - 1;
                if (t < 0) t += TIMESTEPS;
                if ((unsigned)t < TIMESTEPS) atomicMax(&ht[t], genHi | y);
            }
        }
        __builtin_amdgcn_wave_barrier();   // reads stay after this row's atomics
        // (DS ops within a wave complete in order; barrier is compiler-only)

        // accumulate: contiguous b128 reads, decode gen tag
        #pragma unroll
        for (int k = 0; k < 4; ++k) {
            const uint4 a = *(const uint4*)&hr[k * 256 + lane * 4];
            const uint4 b = *(const uint4*)&ht[k * 256 + lane * 4];
            const unsigned int ar[4] = {a.x, a.y, a.z, a.w};
            const unsigned int br[4] = {b.x, b.y, b.z, b.w};
            #pragma unroll
            for (int j = 0; j < 4; ++j) {
                unsigned int ur = ar[j] - genHi;
                unsigned int yr = (ur < 256u) ? ur : 0u;
                unsigned int ut = br[j] - genHi;
                unsigned int yt = (ut < 256u) ? ut : 0u;
                int d = (int)yr - (int)yt;
                acc += (unsigned int)(d * d);
            }
        }
        __builtin_amdgcn_wave_barrier();   // next row's atomics stay below reads
    }

    // wave-64 shuffle reduce; one partial per wave, zero contention.
    // (Deliberately NOT fused with a last-block-done counter: 1024
    // same-address device atomics serialize at ~10ns each ≈ +10 µs — the
    // round-1 lesson. The second launch is cheaper.)
    #pragma unroll
    for (int off = 32; off > 0; off >>= 1) acc += __shfl_down(acc, off, 64);
    if (lane == 0) partials[blockIdx.x * WAVES_PER_BLOCK + wave] = acc;
}

// Single block sums 4096 u32 partials exactly in u64.
__global__ __launch_bounds__(256) void reduce_kernel(
    const unsigned int* __restrict__ partials, float* __restrict__ out)
{
    const int tid = threadIdx.x;
    unsigned long long s = 0;
    #pragma unroll
    for (int k = 0; k < 4; ++k) {
        const uint4 p = *(const uint4*)&partials[(k * 256 + tid) * 4];
        s += (unsigned long long)p.x + p.y + p.z + p.w;
    }

    #pragma unroll
    for (int off = 32; off > 0; off >>= 1) s += __shfl_down(s, off, 64);

    __shared__ unsigned long long wsum[4];
    const int wave = tid >> 6;
    if ((tid & 63) == 0) wsum[wave] = s;
    __syncthreads();

    if (tid == 0) {
        unsigned long long tot = wsum[0] + wsum[1] + wsum[2] + wsum[3];
        const double denom = (double)BATCH * (double)HH * (double)TIMESTEPS; // 16,384,000
        out[0] = (float)((double)tot / denom);
    }
}

extern "C" void kernel_launch(void* const* d_in, const int* in_sizes, int n_in,
                              void* d_out, int out_size, void* d_ws, size_t ws_size,
                              hipStream_t stream) {
    const float* rec = (const float*)d_in[0];
    const float* tgt = (const float*)d_in[1];
    float* out = (float*)d_out;
    unsigned int* partials = (unsigned int*)d_ws;   // 4096 * 4 B = 16 KB scratch

    holo_mse_kernel<<<NBLOCKS, 256, 0, stream>>>(rec, tgt, partials);
    reduce_kernel<<<1, 256, 0, stream>>>(partials, out);
}